// Round 5
// baseline (470.121 us; speedup 1.0000x reference)
//
#include <hip/hip_runtime.h>

#define NIN    20
#define NHID   6
#define NOUT   6
#define BS     256   // threads per block = rows per chunk
#define CHUNKS 4     // chunks per block (grid-strided consecutively)
#define PAD    21    // LDS row stride in dwords; odd => 2 lanes/bank = free

__device__ __forceinline__ float fsig(float t) {
    // sigmoid(t) = 1/(1+exp(-t)); v_exp_f32 + v_rcp_f32, ~1e-7 rel error
    return __builtin_amdgcn_rcpf(1.0f + __expf(-t));
}

__global__ __launch_bounds__(BS, 4)
void mlp_fused(const float* __restrict__ x,
               const float* __restrict__ W1,
               const float* __restrict__ W2,
               const float* __restrict__ W5,
               float* __restrict__ out,
               int nrows)
{
    __shared__ float sx[BS * PAD];           // 21504 B -> 7 blocks/CU

    const int t = threadIdx.x;
    const long long block_row0 = (long long)blockIdx.x * (BS * CHUNKS);

    // ---- prefetch chunk 0 into registers (coalesced: lane stride 16 B) ----
    float4 pre[5];
    {
        const float4* __restrict__ p4 = (const float4*)(x + block_row0 * NIN);
        const long long lim4 = ((long long)nrows - block_row0) * 5;  // float4s avail
#pragma unroll
        for (int k = 0; k < 5; ++k) {
            const int i = t + BS * k;
            pre[k] = (i < lim4) ? p4[i] : make_float4(0.f, 0.f, 0.f, 0.f);
        }
    }

#pragma unroll
    for (int c = 0; c < CHUNKS; ++c) {
        const long long chunk_row0 = block_row0 + (long long)c * BS;

        // ---- write prefetched regs -> LDS (transpose into pad-21 rows) ----
#pragma unroll
        for (int k = 0; k < 5; ++k) {
            const int i = t + BS * k;        // float4 index within chunk
            const int r = i / 5;
            const int q = (i % 5) * 4;
            float* d = &sx[r * PAD + q];
            d[0] = pre[k].x; d[1] = pre[k].y; d[2] = pre[k].z; d[3] = pre[k].w;
        }
        __syncthreads();

        // ---- issue NEXT chunk's global loads now; used only after the
        //      trailing barrier, so HBM latency hides under compute (T14) ----
        if (c + 1 < CHUNKS) {
            const long long next_row0 = chunk_row0 + BS;
            const float4* __restrict__ p4 = (const float4*)(x + next_row0 * NIN);
            const long long lim4 = ((long long)nrows - next_row0) * 5;
#pragma unroll
            for (int k = 0; k < 5; ++k) {
                const int i = t + BS * k;
                pre[k] = (i < lim4) ? p4[i] : make_float4(0.f, 0.f, 0.f, 0.f);
            }
        }

        // ---- compute one row from LDS (2 lanes/bank = conflict-free) ----
        const long long row = chunk_row0 + t;
        if (row < nrows) {
            float xr[NIN];
#pragma unroll
            for (int k = 0; k < NIN; ++k) xr[k] = sx[t * PAD + k];

            // weights: uniform pointer + constant offsets -> s_load/SGPR ops
            float h[NHID];
#pragma unroll
            for (int j = 0; j < NHID; ++j) {
                float a = 0.0f;
#pragma unroll
                for (int k = 0; k < NIN; ++k) a = fmaf(xr[k], W1[j * NIN + k], a);
                h[j] = fsig(a);
            }

            float g[NHID];
#pragma unroll
            for (int j = 0; j < NHID; ++j) {
                float a = 0.0f;
#pragma unroll
                for (int k = 0; k < NHID; ++k) a = fmaf(h[k], W2[j * NHID + k], a);
                g[j] = fsig(a);
            }

            float o[NOUT];
#pragma unroll
            for (int j = 0; j < NOUT; ++j) {
                float a = 0.0f;
#pragma unroll
                for (int k = 0; k < NHID; ++k) a = fmaf(g[k], W5[j * NHID + k], a);
                o[j] = a;
            }

            // 24 B/row, 8 B-aligned -> 3x float2, dense across the wave
            float2* __restrict__ op = (float2*)(out + row * NOUT);
            op[0] = make_float2(o[0], o[1]);
            op[1] = make_float2(o[2], o[3]);
            op[2] = make_float2(o[4], o[5]);
        }

        // all LDS readers done before next iteration overwrites sx
        if (c + 1 < CHUNKS) __syncthreads();
    }
}

extern "C" void kernel_launch(void* const* d_in, const int* in_sizes, int n_in,
                              void* d_out, int out_size, void* d_ws, size_t ws_size,
                              hipStream_t stream) {
    const float* x  = (const float*)d_in[0];
    const float* W1 = (const float*)d_in[1];
    const float* W2 = (const float*)d_in[2];
    const float* W5 = (const float*)d_in[3];
    float* out = (float*)d_out;

    const int nrows = in_sizes[0] / NIN;                       // 4194304
    const int rows_per_block = BS * CHUNKS;                    // 1024
    const int grid = (nrows + rows_per_block - 1) / rows_per_block;  // 4096
    mlp_fused<<<grid, BS, 0, stream>>>(x, W1, W2, W5, out, nrows);
}